// Round 3
// baseline (99.459 us; speedup 1.0000x reference)
//
#include <hip/hip_runtime.h>
#include <math.h>

// Both clouds: 16384 x float2.
#define NPTS  16384
#define BLK   256
#define Q     16                     // queries per thread (contiguous)
#define QB    (NPTS / (BLK * Q))     // 4 query-blocks per direction
#define TCH   128                    // target chunks per direction
#define CHUNK (NPTS / TCH)           // 128 targets per chunk
#define G     (CHUNK / 4)            // 32 groups of 4 targets

// ws layout (float): ws[ch][dir*NPTS + q] = per-chunk min d^2 for that query.
// TCH * 2*NPTS * 4 B = 16 MB of workspace. Every slot is written exactly once
// (block (dir,qb,ch) owns [ch][dir*NPTS + qb*4096 .. +4095]), so no init and
// no atomics; harness poison is overwritten before it is read.
//
// Pipe budget per round-2 analysis: VALU 17.1 us/SIMD is the floor; LDS was
// 15.4 us/CU (192 ds_read_b128/wave) and dependent -> serialization. Q=16
// halves LDS instruction pressure (96 reads/wave, 7.7 us/CU) while keeping
// VALU count and 4-blocks/CU residency identical (TCH=128 keeps grid=1024).

__global__ __launch_bounds__(BLK, 4) void cc_min_kernel(
        const float2* __restrict__ pc,    // render points (16384)
        const float2* __restrict__ ref,   // ref points    (16384)
        float* __restrict__ ws,
        float* __restrict__ out) {
    // Per 4-target group g: A(-2x0,-2y0,-2x1,-2y1), B(-2x2,-2y2,-2x3,-2y3),
    // C(z0,z1,z2,z3).  3 broadcast ds_read_b128 per 4 targets.
    __shared__ float s6[G * 12];     // 1.5 KB

    int b   = blockIdx.x;
    int dir = b / (QB * TCH);
    int rem = b % (QB * TCH);
    int qb  = rem / TCH;
    int ch  = rem % TCH;

    // Zero the output accumulator for the (stream-ordered) final kernel.
    if (b == 0 && threadIdx.x == 0) out[0] = 0.0f;

    const float2* __restrict__ qry = dir ? ref : pc;
    const float2* __restrict__ tgt = dir ? pc  : ref;

    if (threadIdx.x < G) {
        int g = threadIdx.x;
        const float4* t4 = (const float4*)tgt + (size_t)ch * (CHUNK / 2);
        float4 p01 = t4[2 * g];       // (x0, y0, x1, y1)
        float4 p23 = t4[2 * g + 1];   // (x2, y2, x3, y3)
        float4* dst = (float4*)&s6[12 * g];
        dst[0] = make_float4(-2.0f * p01.x, -2.0f * p01.y,
                             -2.0f * p01.z, -2.0f * p01.w);
        dst[1] = make_float4(-2.0f * p23.x, -2.0f * p23.y,
                             -2.0f * p23.z, -2.0f * p23.w);
        dst[2] = make_float4(fmaf(p01.x, p01.x, p01.y * p01.y),
                             fmaf(p01.z, p01.z, p01.w * p01.w),
                             fmaf(p23.x, p23.x, p23.y * p23.y),
                             fmaf(p23.z, p23.z, p23.w * p23.w));
    }

    // 16 CONTIGUOUS queries per thread: loads are 8x global_load_dwordx4,
    // wave covers a 4 KB contiguous span (64 B per lane) -> fully coalesced.
    float px[Q], py[Q], pn[Q], m[Q];
    int qbase = qb * (BLK * Q) + threadIdx.x * Q;
    const float4* q4 = (const float4*)(qry + qbase);
#pragma unroll
    for (int j2 = 0; j2 < Q / 2; ++j2) {
        float4 v = q4[j2];
        px[2 * j2]     = v.x;  py[2 * j2]     = v.y;
        px[2 * j2 + 1] = v.z;  py[2 * j2 + 1] = v.w;
        pn[2 * j2]     = fmaf(v.x, v.x, v.y * v.y);
        pn[2 * j2 + 1] = fmaf(v.z, v.z, v.w * v.w);
        m[2 * j2]      = INFINITY;
        m[2 * j2 + 1]  = INFINITY;
    }
    __syncthreads();

    // Surrogate s = |t|^2 - 2q.t.  Per 4 targets per query: 8 FMA + 2 min3.
    // One LDS group-read (3 x b128) per 320 VALU cycles; unroll 2 gives the
    // scheduler a prefetch window.
#pragma unroll 2
    for (int g = 0; g < G; ++g) {
        float4 A = *(const float4*)&s6[12 * g];
        float4 B = *(const float4*)&s6[12 * g + 4];
        float4 C = *(const float4*)&s6[12 * g + 8];
#pragma unroll
        for (int j = 0; j < Q; ++j) {
            float s0 = fmaf(px[j], A.x, fmaf(py[j], A.y, C.x));
            float s1 = fmaf(px[j], A.z, fmaf(py[j], A.w, C.y));
            float s2 = fmaf(px[j], B.x, fmaf(py[j], B.y, C.z));
            float s3 = fmaf(px[j], B.z, fmaf(py[j], B.w, C.w));
            m[j] = fminf(fminf(m[j], s0), s1);   // -> v_min3_f32
            m[j] = fminf(fminf(m[j], s2), s3);   // -> v_min3_f32
        }
    }

    // d^2 = max(min_surrogate + |p|^2, 0); contiguous b128 stores of this
    // block's partial min -- combine happens in cc_final_kernel.
    float* wrow = ws + (size_t)ch * (2 * NPTS) + dir * NPTS + qbase;
#pragma unroll
    for (int j4 = 0; j4 < Q / 4; ++j4) {
        float4 r;
        r.x = fmaxf(m[4 * j4 + 0] + pn[4 * j4 + 0], 0.0f);
        r.y = fmaxf(m[4 * j4 + 1] + pn[4 * j4 + 1], 0.0f);
        r.z = fmaxf(m[4 * j4 + 2] + pn[4 * j4 + 2], 0.0f);
        r.w = fmaxf(m[4 * j4 + 3] + pn[4 * j4 + 3], 0.0f);
        ((float4*)wrow)[j4] = r;
    }
}

// Parallel finish: one thread per (dir,query), 256 blocks x 128 threads.
// 16 independent accumulators -> 16 outstanding loads per batch, 8 batches,
// then tree-min, sqrt, wave reduce, one atomicAdd/wave.
#define FBLK 128
__global__ __launch_bounds__(FBLK) void cc_final_kernel(
        const float* __restrict__ ws, float* __restrict__ out) {
    int q = blockIdx.x * FBLK + threadIdx.x;   // 0 .. 2*NPTS-1

    float mm[16];
#pragma unroll
    for (int k = 0; k < 16; ++k)
        mm[k] = ws[(size_t)k * (2 * NPTS) + q];
#pragma unroll
    for (int ch = 16; ch < TCH; ch += 16) {
#pragma unroll
        for (int k = 0; k < 16; ++k)
            mm[k] = fminf(mm[k], ws[(size_t)(ch + k) * (2 * NPTS) + q]);
    }
#pragma unroll
    for (int s2 = 8; s2 > 0; s2 >>= 1)
#pragma unroll
        for (int k = 0; k < 8; ++k)
            if (k < s2) mm[k] = fminf(mm[k], mm[k + s2]);

    float s = sqrtf(mm[0]);

#pragma unroll
    for (int off = 32; off > 0; off >>= 1)
        s += __shfl_down(s, off, 64);

    if ((threadIdx.x & 63) == 0)
        atomicAdd(out, s);
}

extern "C" void kernel_launch(void* const* d_in, const int* in_sizes, int n_in,
                              void* d_out, int out_size, void* d_ws, size_t ws_size,
                              hipStream_t stream) {
    const float2* pc  = (const float2*)d_in[0];  // img_render_points (128*128*2 f32)
    const float2* ref = (const float2*)d_in[1];  // ref contour (16384*2 f32)
    float* out = (float*)d_out;
    float* ws  = (float*)d_ws;                   // 16 MB used

    // 2 dirs x 4 query-blocks x 128 chunks = 1024 blocks = 4/CU resident
    cc_min_kernel<<<2 * QB * TCH, BLK, 0, stream>>>(pc, ref, ws, out);
    cc_final_kernel<<<(2 * NPTS) / FBLK, FBLK, 0, stream>>>(ws, out);
}